// Round 8
// baseline (184.483 us; speedup 1.0000x reference)
//
#include <hip/hip_runtime.h>
#include <hip/hip_bf16.h>
#include <cstddef>

#define B_   128
#define L_   128
#define H_   1024
#define V_   50000
#define INDIM 1088   // H + 32 + 32

typedef short short8 __attribute__((ext_vector_type(8)));
typedef unsigned short ushort8 __attribute__((ext_vector_type(8)));
typedef unsigned short ushort4v __attribute__((ext_vector_type(4)));
typedef float f32x4 __attribute__((ext_vector_type(4)));

static __device__ __forceinline__ unsigned short f2bf(float f) {
    unsigned u = __builtin_bit_cast(unsigned, f);
    u = u + 0x7FFFu + ((u >> 16) & 1u);
    return (unsigned short)(u >> 16);
}
static __device__ __forceinline__ float bf2f(unsigned short h) {
    unsigned u = ((unsigned)h) << 16;
    return __builtin_bit_cast(float, u);
}
static __device__ __forceinline__ float sigm(float v) {
    return 1.f / (1.f + __expf(-v));
}

// ---------------------------------------------------------------------------
// prep: x = [emb|semb|nemb] and h = lh, both as bf16 hi/lo planes
// ---------------------------------------------------------------------------
__global__ __launch_bounds__(256) void prep_kernel(
    const int* __restrict__ seq, const int* __restrict__ c2n,
    const int* __restrict__ c2f, const float* __restrict__ emb,
    const float* __restrict__ semb, const float* __restrict__ nemb,
    const float* __restrict__ lh,
    unsigned short* __restrict__ x_hi, unsigned short* __restrict__ x_lo,
    unsigned short* __restrict__ h_hi, unsigned short* __restrict__ h_lo)
{
    const int b = blockIdx.x, t = threadIdx.x;
    const int idx = seq[b];
    for (int i = t; i < 528; i += 256) {
        float4 v;
        unsigned short *dh, *dl;
        int off;
        if (i < 272) {
            if (i < 256) {
                v = *(const float4*)&emb[(size_t)idx * H_ + i * 4];
            } else {
                const int j = i - 256;
                if (j < 8) v = *(const float4*)&semb[c2f[idx] * 32 + j * 4];
                else       v = *(const float4*)&nemb[c2n[idx] * 32 + (j - 8) * 4];
            }
            dh = x_hi + (size_t)b * INDIM; dl = x_lo + (size_t)b * INDIM; off = i * 4;
        } else {
            const int j = i - 272;
            v = *(const float4*)&lh[(size_t)b * H_ + j * 4];
            dh = h_hi + (size_t)b * H_; dl = h_lo + (size_t)b * H_; off = j * 4;
        }
        const float fv[4] = {v.x, v.y, v.z, v.w};
        ushort4v hh, ll;
#pragma unroll
        for (int e = 0; e < 4; e++) {
            hh[e] = f2bf(fv[e]);
            ll[e] = f2bf(fv[e] - bf2f(hh[e]));
        }
        *(ushort4v*)&dh[off] = hh;
        *(ushort4v*)&dl[off] = ll;
    }
}

// ---------------------------------------------------------------------------
// Streaming MFMA GEMM body (R4 structure, known-good).
// ---------------------------------------------------------------------------
template<bool WT, bool SPLIT, bool TANH>
static __device__ __forceinline__ void sgemm_body(
    const unsigned short* __restrict__ Ah, const unsigned short* __restrict__ Al, int lda,
    const float* __restrict__ W, int ldw,
    const float* __restrict__ bias,
    float* __restrict__ C, int ldc, size_t pstride,
    int N, int k_len0, int k_lenB)
{
    extern __shared__ char smem_raw[];
    typedef unsigned short RowT[72];
    RowT* As_h = (RowT*)(smem_raw);            // 128 rows * 144 B = 18432
    RowT* Ws_h = (RowT*)(smem_raw + 18432);    //  64 rows           9216
    RowT* As_l = (RowT*)(smem_raw + 27648);    // split only
    RowT* Ws_l = (RowT*)(smem_raw + 46080);    // split only

    const int t    = threadIdx.x;
    const int lane = t & 63;
    const int wv   = t >> 6;
    const int wr   = wv >> 1;
    const int wc   = wv & 1;
    const int n0   = blockIdx.x * 64;
    const int l15  = lane & 15;
    const int g    = lane >> 4;

    const int y     = blockIdx.y;
    const int k_off = (y == 0) ? 0 : k_len0 + (y - 1) * k_lenB;
    const int k_len = (y == 0) ? k_len0 : k_lenB;
    float* Cp = C + (size_t)y * pstride;

    const int ar = t >> 3;
    const int ac = (t & 7) * 8;
    const int wn = t >> 2, wq = t & 3;
    const int nk = t >> 4, nn4 = (t & 15) * 4;

    f32x4 acc[4][2];
#pragma unroll
    for (int i = 0; i < 4; i++)
#pragma unroll
        for (int j = 0; j < 2; j++) acc[i][j] = (f32x4){0.f, 0.f, 0.f, 0.f};

#define LOAD_A(K0, RA, RAL) do {                                               \
    _Pragma("unroll")                                                          \
    for (int i_ = 0; i_ < 4; i_++)                                             \
        RA[i_] = *(const ushort8*)&Ah[(size_t)(ar + i_ * 32) * lda + (K0) + ac]; \
    if constexpr (SPLIT) {                                                     \
        _Pragma("unroll")                                                      \
        for (int i_ = 0; i_ < 4; i_++)                                         \
            RAL[i_] = *(const ushort8*)&Al[(size_t)(ar + i_ * 32) * lda + (K0) + ac]; \
    }                                                                          \
} while (0)

#define LOAD_W(K0, RW) do {                                                    \
    if constexpr (WT) {                                                        \
        const bool ok_ = (n0 + wn) < N;                                        \
        const float* wb_ = W + (size_t)(n0 + wn) * ldw + (K0);                 \
        _Pragma("unroll")                                                      \
        for (int j_ = 0; j_ < 4; j_++)                                         \
            RW[j_] = ok_ ? *(const float4*)&wb_[j_ * 16 + wq * 4]              \
                         : make_float4(0.f, 0.f, 0.f, 0.f);                    \
    } else {                                                                   \
        _Pragma("unroll")                                                      \
        for (int j_ = 0; j_ < 4; j_++)                                         \
            RW[j_] = *(const float4*)&W[(size_t)((K0) + nk + j_ * 16) * ldw + n0 + nn4]; \
    }                                                                          \
} while (0)

#define STAGE_REGS(RA, RAL, RW) do {                                           \
    _Pragma("unroll")                                                          \
    for (int i_ = 0; i_ < 4; i_++) {                                           \
        *(ushort8*)&As_h[ar + i_ * 32][ac] = RA[i_];                           \
        if constexpr (SPLIT) *(ushort8*)&As_l[ar + i_ * 32][ac] = RAL[i_];     \
    }                                                                          \
    if constexpr (WT) {                                                        \
        _Pragma("unroll")                                                      \
        for (int j_ = 0; j_ < 4; j_++) {                                       \
            const float fv_[4] = {RW[j_].x, RW[j_].y, RW[j_].z, RW[j_].w};     \
            ushort4v hh_, ll_;                                                 \
            _Pragma("unroll")                                                  \
            for (int e_ = 0; e_ < 4; e_++) {                                   \
                hh_[e_] = f2bf(fv_[e_]);                                       \
                if constexpr (SPLIT) ll_[e_] = f2bf(fv_[e_] - bf2f(hh_[e_]));  \
            }                                                                  \
            *(ushort4v*)&Ws_h[wn][j_ * 16 + wq * 4] = hh_;                     \
            if constexpr (SPLIT) *(ushort4v*)&Ws_l[wn][j_ * 16 + wq * 4] = ll_; \
        }                                                                      \
    } else {                                                                   \
        _Pragma("unroll")                                                      \
        for (int j_ = 0; j_ < 4; j_++) {                                       \
            const float fv_[4] = {RW[j_].x, RW[j_].y, RW[j_].z, RW[j_].w};     \
            _Pragma("unroll")                                                  \
            for (int e_ = 0; e_ < 4; e_++) {                                   \
                const unsigned short hb_ = f2bf(fv_[e_]);                      \
                Ws_h[nn4 + e_][nk + j_ * 16] = hb_;                            \
                if constexpr (SPLIT)                                           \
                    Ws_l[nn4 + e_][nk + j_ * 16] = f2bf(fv_[e_] - bf2f(hb_));  \
            }                                                                  \
        }                                                                      \
    }                                                                          \
} while (0)

    const int k_end = k_off + k_len;

    ushort8 ra[4], ral[4], nra[4], nral[4];
    float4 rw0[4], rw1[4], rw2[4];

    LOAD_A(k_off, ra, ral);
    LOAD_W(k_off, rw0);
    if constexpr (!SPLIT) {
        if (k_off + 64 < k_end) LOAD_W(k_off + 64, rw1);
    }

    for (int k0 = k_off; k0 < k_end; k0 += 64) {
        const bool m1 = (k0 + 64) < k_end;
        const bool m2 = (k0 + 128) < k_end;
        if (m1) {
            LOAD_A(k0 + 64, nra, nral);
            if constexpr (SPLIT) LOAD_W(k0 + 64, rw1);
        }

        STAGE_REGS(ra, ral, rw0);
        __syncthreads();

        if constexpr (!SPLIT) {
            if (m2) LOAD_W(k0 + 128, rw2);
        }

#pragma unroll
        for (int ks = 0; ks < 2; ks++) {
            const int ko = ks * 32 + g * 8;
            short8 ah[4], bh[2];
#pragma unroll
            for (int mi = 0; mi < 4; mi++)
                ah[mi] = *(const short8*)&As_h[wr * 64 + mi * 16 + l15][ko];
#pragma unroll
            for (int ni = 0; ni < 2; ni++)
                bh[ni] = *(const short8*)&Ws_h[wc * 32 + ni * 16 + l15][ko];
            if constexpr (SPLIT) {
                short8 al[4], bl[2];
#pragma unroll
                for (int mi = 0; mi < 4; mi++)
                    al[mi] = *(const short8*)&As_l[wr * 64 + mi * 16 + l15][ko];
#pragma unroll
                for (int ni = 0; ni < 2; ni++)
                    bl[ni] = *(const short8*)&Ws_l[wc * 32 + ni * 16 + l15][ko];
#pragma unroll
                for (int mi = 0; mi < 4; mi++)
#pragma unroll
                    for (int ni = 0; ni < 2; ni++) {
                        acc[mi][ni] = __builtin_amdgcn_mfma_f32_16x16x32_bf16(ah[mi], bh[ni], acc[mi][ni], 0, 0, 0);
                        acc[mi][ni] = __builtin_amdgcn_mfma_f32_16x16x32_bf16(ah[mi], bl[ni], acc[mi][ni], 0, 0, 0);
                        acc[mi][ni] = __builtin_amdgcn_mfma_f32_16x16x32_bf16(al[mi], bh[ni], acc[mi][ni], 0, 0, 0);
                    }
            } else {
#pragma unroll
                for (int mi = 0; mi < 4; mi++)
#pragma unroll
                    for (int ni = 0; ni < 2; ni++)
                        acc[mi][ni] = __builtin_amdgcn_mfma_f32_16x16x32_bf16(ah[mi], bh[ni], acc[mi][ni], 0, 0, 0);
            }
        }
        __syncthreads();

        if (m1) {
#pragma unroll
            for (int i = 0; i < 4; i++) {
                ra[i] = nra[i];
                if constexpr (SPLIT) ral[i] = nral[i];
            }
#pragma unroll
            for (int j = 0; j < 4; j++) {
                rw0[j] = rw1[j];
                if constexpr (!SPLIT) rw1[j] = rw2[j];
            }
        }
    }
#undef LOAD_A
#undef LOAD_W
#undef STAGE_REGS

#pragma unroll
    for (int mi = 0; mi < 4; mi++) {
#pragma unroll
        for (int ni = 0; ni < 2; ni++) {
            const int col = n0 + wc * 32 + ni * 16 + l15;
            if (col < N) {
                const float bb = bias ? bias[col] : 0.f;
#pragma unroll
                for (int r = 0; r < 4; r++) {
                    const int row = wr * 64 + mi * 16 + g * 4 + r;
                    float v = acc[mi][ni][r] + bb;
                    if (TANH) v = tanhf(v);
                    Cp[(size_t)row * ldc + col] = v;
                }
            }
        }
    }
}

template<bool WT, bool SPLIT, bool TANH>
__global__ __launch_bounds__(256, 2) void sgemm(
    const unsigned short* __restrict__ Ah, const unsigned short* __restrict__ Al, int lda,
    const float* __restrict__ W, int ldw,
    const float* __restrict__ bias,
    float* __restrict__ C, int ldc, size_t pstride,
    int N, int k_len0, int k_lenB)
{
    sgemm_body<WT, SPLIT, TANH>(Ah, Al, lda, W, ldw, bias, C, ldc, pstride, N, k_len0, k_lenB);
}

// Merged gi+gh launch: blockIdx.z selects parameter set.
// z==2: L3-warm sweep over W_out (192 blocks grid-stride-read all 205 MB;
// sum kept live via asm sink — no stores, deterministic). Warming during this
// compute-bound window makes op10's W_out reads L3-hits (evidence: R2 op10
// FETCH_SIZE=103MB < 205MB — L3 retains W_out across dispatches).
__global__ __launch_bounds__(256, 2) void gru_gemm(
    const unsigned short* __restrict__ x_hi, const unsigned short* __restrict__ x_lo,
    const float* __restrict__ W_ih,
    const unsigned short* __restrict__ h_hi, const unsigned short* __restrict__ h_lo,
    const float* __restrict__ W_hh,
    const float* __restrict__ W_out,
    float* __restrict__ gi, float* __restrict__ gh)
{
    if (blockIdx.z == 0) {
        sgemm_body<true, true, false>(x_hi, x_lo, INDIM, W_ih, INDIM, nullptr,
                                      gi, 3072, (size_t)128 * 3072, 3072, 320, 256);
    } else if (blockIdx.z == 1) {
        sgemm_body<true, true, false>(h_hi, h_lo, H_, W_hh, H_, nullptr,
                                      gh, 3072, (size_t)128 * 3072, 3072, 256, 256);
    } else {
        // L3 warm: 192 blocks x 256 threads, float4 grid-stride, unroll 8
        const size_t nf4 = (size_t)V_ * H_ / 4;          // 12.8e6 float4
        const size_t stride = 192u * 256u;
        const float4* w4 = (const float4*)W_out;
        size_t i = (size_t)(blockIdx.y * 48 + blockIdx.x) * 256 + threadIdx.x;
        float s = 0.f;
        while (i + 7 * stride < nf4) {
#pragma unroll
            for (int u = 0; u < 8; u++) {
                float4 v = w4[i + (size_t)u * stride];
                s += v.x + v.y + v.z + v.w;
            }
            i += 8 * stride;
        }
        for (; i < nf4; i += stride) {
            float4 v = w4[i];
            s += v.x + v.y + v.z + v.w;
        }
        asm volatile("" :: "v"(s));   // keep loads live (rule #17)
    }
}

// ---------------------------------------------------------------------------
// GRU gates: sums 4 k-slice partials of gi/gh, adds biases, computes h.
// ---------------------------------------------------------------------------
__global__ __launch_bounds__(256) void gru_gates_kernel(
    const float* __restrict__ gi, const float* __restrict__ gh,
    const float* __restrict__ b_ih, const float* __restrict__ b_hh,
    const float* __restrict__ h_prev,
    float* __restrict__ hid_out,
    unsigned short* __restrict__ cat_hi, unsigned short* __restrict__ cat_lo)
{
    const int id = blockIdx.x * 256 + threadIdx.x;
    const int b = id >> 10, j = id & 1023;
    const size_t base = (size_t)b * 3072 + j;
    float ir = b_ih[j], iz = b_ih[1024 + j], in_ = b_ih[2048 + j];
    float hr = b_hh[j], hz = b_hh[1024 + j], hn = b_hh[2048 + j];
#pragma unroll
    for (int p = 0; p < 4; p++) {
        const float* gp = gi + (size_t)p * (128 * 3072);
        const float* hp = gh + (size_t)p * (128 * 3072);
        ir += gp[base]; iz += gp[base + 1024]; in_ += gp[base + 2048];
        hr += hp[base]; hz += hp[base + 1024]; hn += hp[base + 2048];
    }
    const float r = sigm(ir + hr);
    const float z = sigm(iz + hz);
    const float n = tanhf(in_ + r * hn);
    const float h = (1.f - z) * n + z * h_prev[id];
    hid_out[id] = h;
    const unsigned short hb = f2bf(h);
    cat_hi[(size_t)b * 2048 + j] = hb;
    cat_lo[(size_t)b * 2048 + j] = f2bf(h - bf2f(hb));
}

// ---------------------------------------------------------------------------
// energies (partial over 4 h-slices); 512 thr = 8 waves, 16 l each.
// ---------------------------------------------------------------------------
__global__ __launch_bounds__(512) void energy_partial_kernel(
    const float* __restrict__ qp, const float* __restrict__ enc,
    float* __restrict__ epart)
{
    const int s = blockIdx.x, b = blockIdx.y;
    const int t = threadIdx.x, lane = t & 63, wv = t >> 6;
    __shared__ float q_s[256];
    if (t < 256) {
        const size_t o = (size_t)b * H_ + s * 256 + t;
        q_s[t] = qp[o] + qp[o + 131072] + qp[o + 262144] + qp[o + 393216];
    }
    __syncthreads();
    const float4 qv = *(const float4*)&q_s[lane * 4];
    const float* encb = enc + (size_t)b * H_ + s * 256;
    for (int l0 = 0; l0 < 16; l0++) {
        const int l = wv * 16 + l0;
        float4 ev = *(const float4*)&encb[(size_t)l * (B_ * H_) + lane * 4];
        float p = ev.x * qv.x + ev.y * qv.y + ev.z * qv.z + ev.w * qv.w;
#pragma unroll
        for (int off = 32; off > 0; off >>= 1) p += __shfl_xor(p, off);
        if (lane == 0) epart[((size_t)b * 128 + l) * 4 + s] = p;
    }
}

// ---------------------------------------------------------------------------
// Fused softmax + context; s==0 writes attnw.
// ---------------------------------------------------------------------------
__global__ __launch_bounds__(256) void context_softmax_kernel(
    const float* __restrict__ epart, const float* __restrict__ enc,
    unsigned short* __restrict__ cat_hi, float* __restrict__ attnw)
{
    const int s = blockIdx.x, b = blockIdx.y, t = threadIdx.x;
    const int lane = t & 63, wv = t >> 6;
    __shared__ float w_s[128];
    __shared__ float red[4];

    float e = -INFINITY;
    if (t < 128) {
        float4 pe = *(const float4*)&epart[((size_t)b * 128 + t) * 4];
        e = pe.x + pe.y + pe.z + pe.w;
    }
    float mx = e;
#pragma unroll
    for (int off = 32; off > 0; off >>= 1) mx = fmaxf(mx, __shfl_xor(mx, off));
    if (lane == 0) red[wv] = mx;
    __syncthreads();
    const float gm = fmaxf(fmaxf(red[0], red[1]), fmaxf(red[2], red[3]));
    __syncthreads();
    float ex = (t < 128) ? __expf(e - gm) : 0.f;
    float sm = ex;
#pragma unroll
    for (int off = 32; off > 0; off >>= 1) sm += __shfl_xor(sm, off);
    if (lane == 0) red[wv] = sm;
    __syncthreads();
    const float gs = red[0] + red[1] + red[2] + red[3];
    if (t < 128) {
        const float w = ex / gs;
        w_s[t] = w;
        if (s == 0) attnw[(size_t)b * L_ + t] = w;
    }
    __syncthreads();

    const int h = s * 256 + t;
    const float* encb = enc + (size_t)b * H_ + h;
    float c = 0.f;
#pragma unroll 4
    for (int l = 0; l < 128; l++)
        c += w_s[l] * encb[(size_t)l * (B_ * H_)];
    cat_hi[(size_t)b * 2048 + 1024 + h] = f2bf(c);
}

// co = tanh(sum of 4 partials + b_cat) -> bf16
__global__ __launch_bounds__(256) void co_reduce_kernel(
    const float* __restrict__ co_part, const float* __restrict__ b_cat,
    unsigned short* __restrict__ co_hi)
{
    const int id = blockIdx.x * 256 + threadIdx.x;
    const int j = id & 1023;
    float s = b_cat[j];
#pragma unroll
    for (int p = 0; p < 4; p++) s += co_part[(size_t)p * 131072 + id];
    co_hi[id] = f2bf(tanhf(s));
}

// ---------------------------------------------------------------------------
extern "C" void kernel_launch(void* const* d_in, const int* in_sizes, int n_in,
                              void* d_out, int out_size, void* d_ws, size_t ws_size,
                              hipStream_t stream)
{
    const int*   seq    = (const int*)  d_in[0];
    const float* lh     = (const float*)d_in[1];
    const float* enc    = (const float*)d_in[2];
    const int*   c2n    = (const int*)  d_in[3];
    const int*   c2f    = (const int*)  d_in[4];
    const float* emb    = (const float*)d_in[5];
    const float* semb   = (const float*)d_in[6];
    const float* nemb   = (const float*)d_in[7];
    const float* W_ih   = (const float*)d_in[8];
    const float* W_hh   = (const float*)d_in[9];
    const float* b_ih   = (const float*)d_in[10];
    const float* b_hh   = (const float*)d_in[11];
    const float* W_attn = (const float*)d_in[12];
    // d_in[13] = b_attn: dropped (softmax shift-invariant, exact)
    const float* W_cat  = (const float*)d_in[14];
    const float* b_cat  = (const float*)d_in[15];
    const float* W_out  = (const float*)d_in[16];
    const float* b_out  = (const float*)d_in[17];

    float* out    = (float*)d_out;
    float* hidden = out + (size_t)B_ * V_;
    float* attnw  = hidden + (size_t)B_ * H_;

    // ---- workspace layout ----
    unsigned short* x_hi   = (unsigned short*)d_ws;            // 128*1088
    unsigned short* x_lo   = x_hi   + (size_t)128 * INDIM;
    unsigned short* h_hi   = x_lo   + (size_t)128 * INDIM;     // 128*1024
    unsigned short* h_lo   = h_hi   + (size_t)128 * 1024;
    unsigned short* cat_hi = h_lo   + (size_t)128 * 1024;      // 128*2048
    unsigned short* cat_lo = cat_hi + (size_t)128 * 2048;
    unsigned short* co_hi  = cat_lo + (size_t)128 * 2048;      // 128*1024
    float* fbase   = (float*)(co_hi + (size_t)128 * 1024);
    float* gi_part = fbase;                                    // 4*128*3072
    float* gh_part = gi_part + (size_t)4 * 128 * 3072;         // 4*128*3072
    // aliases (gi/gh dead after gates):
    float* q_part  = fbase;                                    // 4*128*1024
    float* co_part = q_part + (size_t)4 * 128 * 1024;          // 4*128*1024
    float* epart   = co_part + (size_t)4 * 128 * 1024;         // 128*128*4

    const int SMEM_SPLIT = 55296;
    const int SMEM_PLAIN = 27648;

    // 1. prep: x, h bf16 hi/lo planes
    hipLaunchKernelGGL(prep_kernel, dim3(B_), dim3(256), 0, stream,
                       seq, c2n, c2f, emb, semb, nemb, lh, x_hi, x_lo, h_hi, h_lo);
    // 2+3. gi & gh partials in one dispatch (z selects) + W_out L3-warm (z==2)
    hipLaunchKernelGGL(gru_gemm, dim3(48, 4, 3), dim3(256), SMEM_SPLIT, stream,
                       x_hi, x_lo, W_ih, h_hi, h_lo, W_hh, W_out, gi_part, gh_part);
    // 4. gates -> hidden + cat planes
    hipLaunchKernelGGL(gru_gates_kernel, dim3(512), dim3(256), 0, stream,
                       gi_part, gh_part, b_ih, b_hh, lh, hidden, cat_hi, cat_lo);
    // 5. q partials = h @ W_attn (NT, split): K=1024 -> 4 x 256
    hipLaunchKernelGGL((sgemm<false, true, false>), dim3(16, 4), dim3(256), SMEM_SPLIT, stream,
                       cat_hi, cat_lo, 2048, W_attn, H_, (const float*)nullptr,
                       q_part, H_, (size_t)128 * 1024, H_, 256, 256);
    // 6. energies
    hipLaunchKernelGGL(energy_partial_kernel, dim3(4, 128), dim3(512), 0, stream,
                       q_part, enc, epart);
    // 7. softmax + context fused
    hipLaunchKernelGGL(context_softmax_kernel, dim3(4, 128), dim3(256), 0, stream,
                       epart, enc, cat_hi, attnw);
    // 8. co partials = cat @ W_cat.T: K=2048 -> 4 x 512
    hipLaunchKernelGGL((sgemm<true, false, false>), dim3(16, 4), dim3(256), SMEM_PLAIN, stream,
                       cat_hi, cat_hi, 2048, W_cat, 2048, (const float*)nullptr,
                       co_part, H_, (size_t)128 * 1024, H_, 512, 512);
    // 9. co = tanh(sum + b_cat) -> bf16
    hipLaunchKernelGGL(co_reduce_kernel, dim3(512), dim3(256), 0, stream,
                       co_part, b_cat, co_hi);
    // 10. out = co @ W_out.T + b_out (depth-2 W prefetch; W now L3-warm)
    hipLaunchKernelGGL((sgemm<true, false, false>), dim3((V_ + 63) / 64, 1), dim3(256), SMEM_PLAIN, stream,
                       co_hi, co_hi, H_, W_out, H_, b_out,
                       out, V_, (size_t)0, V_, H_, H_);
}

// Round 9
// 154.014 us; speedup vs baseline: 1.1978x; 1.1978x over previous
//
#include <hip/hip_runtime.h>
#include <hip/hip_bf16.h>
#include <cstddef>

#define B_   128
#define L_   128
#define H_   1024
#define V_   50000
#define INDIM 1088   // H + 32 + 32

typedef short short8 __attribute__((ext_vector_type(8)));
typedef unsigned short ushort8 __attribute__((ext_vector_type(8)));
typedef unsigned short ushort4v __attribute__((ext_vector_type(4)));
typedef float f32x4 __attribute__((ext_vector_type(4)));

static __device__ __forceinline__ unsigned short f2bf(float f) {
    unsigned u = __builtin_bit_cast(unsigned, f);
    u = u + 0x7FFFu + ((u >> 16) & 1u);
    return (unsigned short)(u >> 16);
}
static __device__ __forceinline__ float bf2f(unsigned short h) {
    unsigned u = ((unsigned)h) << 16;
    return __builtin_bit_cast(float, u);
}
static __device__ __forceinline__ float sigm(float v) {
    return 1.f / (1.f + __expf(-v));
}

// ---------------------------------------------------------------------------
// prep: x = [emb|semb|nemb] and h = lh, both as bf16 hi/lo planes
// ---------------------------------------------------------------------------
__global__ __launch_bounds__(256) void prep_kernel(
    const int* __restrict__ seq, const int* __restrict__ c2n,
    const int* __restrict__ c2f, const float* __restrict__ emb,
    const float* __restrict__ semb, const float* __restrict__ nemb,
    const float* __restrict__ lh,
    unsigned short* __restrict__ x_hi, unsigned short* __restrict__ x_lo,
    unsigned short* __restrict__ h_hi, unsigned short* __restrict__ h_lo)
{
    const int b = blockIdx.x, t = threadIdx.x;
    const int idx = seq[b];
    for (int i = t; i < 528; i += 256) {
        float4 v;
        unsigned short *dh, *dl;
        int off;
        if (i < 272) {
            if (i < 256) {
                v = *(const float4*)&emb[(size_t)idx * H_ + i * 4];
            } else {
                const int j = i - 256;
                if (j < 8) v = *(const float4*)&semb[c2f[idx] * 32 + j * 4];
                else       v = *(const float4*)&nemb[c2n[idx] * 32 + (j - 8) * 4];
            }
            dh = x_hi + (size_t)b * INDIM; dl = x_lo + (size_t)b * INDIM; off = i * 4;
        } else {
            const int j = i - 272;
            v = *(const float4*)&lh[(size_t)b * H_ + j * 4];
            dh = h_hi + (size_t)b * H_; dl = h_lo + (size_t)b * H_; off = j * 4;
        }
        const float fv[4] = {v.x, v.y, v.z, v.w};
        ushort4v hh, ll;
#pragma unroll
        for (int e = 0; e < 4; e++) {
            hh[e] = f2bf(fv[e]);
            ll[e] = f2bf(fv[e] - bf2f(hh[e]));
        }
        *(ushort4v*)&dh[off] = hh;
        *(ushort4v*)&dl[off] = ll;
    }
}

// ---------------------------------------------------------------------------
// Streaming MFMA GEMM body (R4 structure, known-good).
// ---------------------------------------------------------------------------
template<bool WT, bool SPLIT, bool TANH>
static __device__ __forceinline__ void sgemm_body(
    const unsigned short* __restrict__ Ah, const unsigned short* __restrict__ Al, int lda,
    const float* __restrict__ W, int ldw,
    const float* __restrict__ bias,
    float* __restrict__ C, int ldc, size_t pstride,
    int N, int k_len0, int k_lenB)
{
    extern __shared__ char smem_raw[];
    typedef unsigned short RowT[72];
    RowT* As_h = (RowT*)(smem_raw);            // 128 rows * 144 B = 18432
    RowT* Ws_h = (RowT*)(smem_raw + 18432);    //  64 rows           9216
    RowT* As_l = (RowT*)(smem_raw + 27648);    // split only
    RowT* Ws_l = (RowT*)(smem_raw + 46080);    // split only

    const int t    = threadIdx.x;
    const int lane = t & 63;
    const int wv   = t >> 6;
    const int wr   = wv >> 1;
    const int wc   = wv & 1;
    const int n0   = blockIdx.x * 64;
    const int l15  = lane & 15;
    const int g    = lane >> 4;

    const int y     = blockIdx.y;
    const int k_off = (y == 0) ? 0 : k_len0 + (y - 1) * k_lenB;
    const int k_len = (y == 0) ? k_len0 : k_lenB;
    float* Cp = C + (size_t)y * pstride;

    const int ar = t >> 3;
    const int ac = (t & 7) * 8;
    const int wn = t >> 2, wq = t & 3;
    const int nk = t >> 4, nn4 = (t & 15) * 4;

    f32x4 acc[4][2];
#pragma unroll
    for (int i = 0; i < 4; i++)
#pragma unroll
        for (int j = 0; j < 2; j++) acc[i][j] = (f32x4){0.f, 0.f, 0.f, 0.f};

#define LOAD_A(K0, RA, RAL) do {                                               \
    _Pragma("unroll")                                                          \
    for (int i_ = 0; i_ < 4; i_++)                                             \
        RA[i_] = *(const ushort8*)&Ah[(size_t)(ar + i_ * 32) * lda + (K0) + ac]; \
    if constexpr (SPLIT) {                                                     \
        _Pragma("unroll")                                                      \
        for (int i_ = 0; i_ < 4; i_++)                                         \
            RAL[i_] = *(const ushort8*)&Al[(size_t)(ar + i_ * 32) * lda + (K0) + ac]; \
    }                                                                          \
} while (0)

#define LOAD_W(K0, RW) do {                                                    \
    if constexpr (WT) {                                                        \
        const bool ok_ = (n0 + wn) < N;                                        \
        const float* wb_ = W + (size_t)(n0 + wn) * ldw + (K0);                 \
        _Pragma("unroll")                                                      \
        for (int j_ = 0; j_ < 4; j_++)                                         \
            RW[j_] = ok_ ? *(const float4*)&wb_[j_ * 16 + wq * 4]              \
                         : make_float4(0.f, 0.f, 0.f, 0.f);                    \
    } else {                                                                   \
        _Pragma("unroll")                                                      \
        for (int j_ = 0; j_ < 4; j_++)                                         \
            RW[j_] = *(const float4*)&W[(size_t)((K0) + nk + j_ * 16) * ldw + n0 + nn4]; \
    }                                                                          \
} while (0)

#define STAGE_REGS(RA, RAL, RW) do {                                           \
    _Pragma("unroll")                                                          \
    for (int i_ = 0; i_ < 4; i_++) {                                           \
        *(ushort8*)&As_h[ar + i_ * 32][ac] = RA[i_];                           \
        if constexpr (SPLIT) *(ushort8*)&As_l[ar + i_ * 32][ac] = RAL[i_];     \
    }                                                                          \
    if constexpr (WT) {                                                        \
        _Pragma("unroll")                                                      \
        for (int j_ = 0; j_ < 4; j_++) {                                       \
            const float fv_[4] = {RW[j_].x, RW[j_].y, RW[j_].z, RW[j_].w};     \
            ushort4v hh_, ll_;                                                 \
            _Pragma("unroll")                                                  \
            for (int e_ = 0; e_ < 4; e_++) {                                   \
                hh_[e_] = f2bf(fv_[e_]);                                       \
                if constexpr (SPLIT) ll_[e_] = f2bf(fv_[e_] - bf2f(hh_[e_]));  \
            }                                                                  \
            *(ushort4v*)&Ws_h[wn][j_ * 16 + wq * 4] = hh_;                     \
            if constexpr (SPLIT) *(ushort4v*)&Ws_l[wn][j_ * 16 + wq * 4] = ll_; \
        }                                                                      \
    } else {                                                                   \
        _Pragma("unroll")                                                      \
        for (int j_ = 0; j_ < 4; j_++) {                                       \
            const float fv_[4] = {RW[j_].x, RW[j_].y, RW[j_].z, RW[j_].w};     \
            _Pragma("unroll")                                                  \
            for (int e_ = 0; e_ < 4; e_++) {                                   \
                const unsigned short hb_ = f2bf(fv_[e_]);                      \
                Ws_h[nn4 + e_][nk + j_ * 16] = hb_;                            \
                if constexpr (SPLIT)                                           \
                    Ws_l[nn4 + e_][nk + j_ * 16] = f2bf(fv_[e_] - bf2f(hb_));  \
            }                                                                  \
        }                                                                      \
    }                                                                          \
} while (0)

    const int k_end = k_off + k_len;

    ushort8 ra[4], ral[4], nra[4], nral[4];
    float4 rw0[4], rw1[4], rw2[4];

    LOAD_A(k_off, ra, ral);
    LOAD_W(k_off, rw0);
    if constexpr (!SPLIT) {
        if (k_off + 64 < k_end) LOAD_W(k_off + 64, rw1);
    }

    for (int k0 = k_off; k0 < k_end; k0 += 64) {
        const bool m1 = (k0 + 64) < k_end;
        const bool m2 = (k0 + 128) < k_end;
        if (m1) {
            LOAD_A(k0 + 64, nra, nral);
            if constexpr (SPLIT) LOAD_W(k0 + 64, rw1);
        }

        STAGE_REGS(ra, ral, rw0);
        __syncthreads();

        if constexpr (!SPLIT) {
            if (m2) LOAD_W(k0 + 128, rw2);
        }

#pragma unroll
        for (int ks = 0; ks < 2; ks++) {
            const int ko = ks * 32 + g * 8;
            short8 ah[4], bh[2];
#pragma unroll
            for (int mi = 0; mi < 4; mi++)
                ah[mi] = *(const short8*)&As_h[wr * 64 + mi * 16 + l15][ko];
#pragma unroll
            for (int ni = 0; ni < 2; ni++)
                bh[ni] = *(const short8*)&Ws_h[wc * 32 + ni * 16 + l15][ko];
            if constexpr (SPLIT) {
                short8 al[4], bl[2];
#pragma unroll
                for (int mi = 0; mi < 4; mi++)
                    al[mi] = *(const short8*)&As_l[wr * 64 + mi * 16 + l15][ko];
#pragma unroll
                for (int ni = 0; ni < 2; ni++)
                    bl[ni] = *(const short8*)&Ws_l[wc * 32 + ni * 16 + l15][ko];
#pragma unroll
                for (int mi = 0; mi < 4; mi++)
#pragma unroll
                    for (int ni = 0; ni < 2; ni++) {
                        acc[mi][ni] = __builtin_amdgcn_mfma_f32_16x16x32_bf16(ah[mi], bh[ni], acc[mi][ni], 0, 0, 0);
                        acc[mi][ni] = __builtin_amdgcn_mfma_f32_16x16x32_bf16(ah[mi], bl[ni], acc[mi][ni], 0, 0, 0);
                        acc[mi][ni] = __builtin_amdgcn_mfma_f32_16x16x32_bf16(al[mi], bh[ni], acc[mi][ni], 0, 0, 0);
                    }
            } else {
#pragma unroll
                for (int mi = 0; mi < 4; mi++)
#pragma unroll
                    for (int ni = 0; ni < 2; ni++)
                        acc[mi][ni] = __builtin_amdgcn_mfma_f32_16x16x32_bf16(ah[mi], bh[ni], acc[mi][ni], 0, 0, 0);
            }
        }
        __syncthreads();

        if (m1) {
#pragma unroll
            for (int i = 0; i < 4; i++) {
                ra[i] = nra[i];
                if constexpr (SPLIT) ral[i] = nral[i];
            }
#pragma unroll
            for (int j = 0; j < 4; j++) {
                rw0[j] = rw1[j];
                if constexpr (!SPLIT) rw1[j] = rw2[j];
            }
        }
    }
#undef LOAD_A
#undef LOAD_W
#undef STAGE_REGS

#pragma unroll
    for (int mi = 0; mi < 4; mi++) {
#pragma unroll
        for (int ni = 0; ni < 2; ni++) {
            const int col = n0 + wc * 32 + ni * 16 + l15;
            if (col < N) {
                const float bb = bias ? bias[col] : 0.f;
#pragma unroll
                for (int r = 0; r < 4; r++) {
                    const int row = wr * 64 + mi * 16 + g * 4 + r;
                    float v = acc[mi][ni][r] + bb;
                    if (TANH) v = tanhf(v);
                    Cp[(size_t)row * ldc + col] = v;
                }
            }
        }
    }
}

template<bool WT, bool SPLIT, bool TANH>
__global__ __launch_bounds__(256, 2) void sgemm(
    const unsigned short* __restrict__ Ah, const unsigned short* __restrict__ Al, int lda,
    const float* __restrict__ W, int ldw,
    const float* __restrict__ bias,
    float* __restrict__ C, int ldc, size_t pstride,
    int N, int k_len0, int k_lenB)
{
    sgemm_body<WT, SPLIT, TANH>(Ah, Al, lda, W, ldw, bias, C, ldc, pstride, N, k_len0, k_lenB);
}

// Merged gi+gh launch: blockIdx.z selects parameter set. PLAIN bf16
// (split dropped: δh ≈ 5e-3 ≪ 6.1e-2 threshold; halves LDS + staging,
// cuts 3x MFMA -> ~2x faster window).
__global__ __launch_bounds__(256, 2) void gru_gemm(
    const unsigned short* __restrict__ x_hi,
    const float* __restrict__ W_ih,
    const unsigned short* __restrict__ h_hi,
    const float* __restrict__ W_hh,
    float* __restrict__ gi, float* __restrict__ gh)
{
    if (blockIdx.z == 0)
        sgemm_body<true, false, false>(x_hi, x_hi, INDIM, W_ih, INDIM, nullptr,
                                       gi, 3072, (size_t)128 * 3072, 3072, 320, 256);
    else
        sgemm_body<true, false, false>(h_hi, h_hi, H_, W_hh, H_, nullptr,
                                       gh, 3072, (size_t)128 * 3072, 3072, 256, 256);
}

// Merged q (split, z=0) + W_cat h-half (plain, z=1, K in [0,1024) -> co_part
// slices 0/1). Both depend only on gates; h-half of the cat GEMM overlaps
// into the q window instead of serializing after context.
__global__ __launch_bounds__(256, 2) void q_cat_kernel(
    const unsigned short* __restrict__ cat_hi, const unsigned short* __restrict__ cat_lo,
    const float* __restrict__ W_attn, const float* __restrict__ W_cat,
    float* __restrict__ q_part, float* __restrict__ co_part)
{
    if (blockIdx.z == 0) {
        sgemm_body<false, true, false>(cat_hi, cat_lo, 2048, W_attn, H_, nullptr,
                                       q_part, H_, (size_t)128 * 1024, H_, 256, 256);
    } else {
        if (blockIdx.y >= 2) return;   // h-half uses 2 k-slices of 512
        sgemm_body<true, false, false>(cat_hi, cat_hi, 2048, W_cat, 2048, nullptr,
                                       co_part, H_, (size_t)128 * 1024, H_, 512, 512);
    }
}

// ---------------------------------------------------------------------------
// GRU gates: sums 4 k-slice partials of gi/gh, adds biases, computes h.
// ---------------------------------------------------------------------------
__global__ __launch_bounds__(256) void gru_gates_kernel(
    const float* __restrict__ gi, const float* __restrict__ gh,
    const float* __restrict__ b_ih, const float* __restrict__ b_hh,
    const float* __restrict__ h_prev,
    float* __restrict__ hid_out,
    unsigned short* __restrict__ cat_hi, unsigned short* __restrict__ cat_lo)
{
    const int id = blockIdx.x * 256 + threadIdx.x;
    const int b = id >> 10, j = id & 1023;
    const size_t base = (size_t)b * 3072 + j;
    float ir = b_ih[j], iz = b_ih[1024 + j], in_ = b_ih[2048 + j];
    float hr = b_hh[j], hz = b_hh[1024 + j], hn = b_hh[2048 + j];
#pragma unroll
    for (int p = 0; p < 4; p++) {
        const float* gp = gi + (size_t)p * (128 * 3072);
        const float* hp = gh + (size_t)p * (128 * 3072);
        ir += gp[base]; iz += gp[base + 1024]; in_ += gp[base + 2048];
        hr += hp[base]; hz += hp[base + 1024]; hn += hp[base + 2048];
    }
    const float r = sigm(ir + hr);
    const float z = sigm(iz + hz);
    const float n = tanhf(in_ + r * hn);
    const float h = (1.f - z) * n + z * h_prev[id];
    hid_out[id] = h;
    const unsigned short hb = f2bf(h);
    cat_hi[(size_t)b * 2048 + j] = hb;
    cat_lo[(size_t)b * 2048 + j] = f2bf(h - bf2f(hb));
}

// ---------------------------------------------------------------------------
// energies (partial over 4 h-slices); 512 thr = 8 waves, 16 l each.
// ---------------------------------------------------------------------------
__global__ __launch_bounds__(512) void energy_partial_kernel(
    const float* __restrict__ qp, const float* __restrict__ enc,
    float* __restrict__ epart)
{
    const int s = blockIdx.x, b = blockIdx.y;
    const int t = threadIdx.x, lane = t & 63, wv = t >> 6;
    __shared__ float q_s[256];
    if (t < 256) {
        const size_t o = (size_t)b * H_ + s * 256 + t;
        q_s[t] = qp[o] + qp[o + 131072] + qp[o + 262144] + qp[o + 393216];
    }
    __syncthreads();
    const float4 qv = *(const float4*)&q_s[lane * 4];
    const float* encb = enc + (size_t)b * H_ + s * 256;
    for (int l0 = 0; l0 < 16; l0++) {
        const int l = wv * 16 + l0;
        float4 ev = *(const float4*)&encb[(size_t)l * (B_ * H_) + lane * 4];
        float p = ev.x * qv.x + ev.y * qv.y + ev.z * qv.z + ev.w * qv.w;
#pragma unroll
        for (int off = 32; off > 0; off >>= 1) p += __shfl_xor(p, off);
        if (lane == 0) epart[((size_t)b * 128 + l) * 4 + s] = p;
    }
}

// ---------------------------------------------------------------------------
// Fused softmax + context; s==0 writes attnw.
// ---------------------------------------------------------------------------
__global__ __launch_bounds__(256) void context_softmax_kernel(
    const float* __restrict__ epart, const float* __restrict__ enc,
    unsigned short* __restrict__ cat_hi, float* __restrict__ attnw)
{
    const int s = blockIdx.x, b = blockIdx.y, t = threadIdx.x;
    const int lane = t & 63, wv = t >> 6;
    __shared__ float w_s[128];
    __shared__ float red[4];

    float e = -INFINITY;
    if (t < 128) {
        float4 pe = *(const float4*)&epart[((size_t)b * 128 + t) * 4];
        e = pe.x + pe.y + pe.z + pe.w;
    }
    float mx = e;
#pragma unroll
    for (int off = 32; off > 0; off >>= 1) mx = fmaxf(mx, __shfl_xor(mx, off));
    if (lane == 0) red[wv] = mx;
    __syncthreads();
    const float gm = fmaxf(fmaxf(red[0], red[1]), fmaxf(red[2], red[3]));
    __syncthreads();
    float ex = (t < 128) ? __expf(e - gm) : 0.f;
    float sm = ex;
#pragma unroll
    for (int off = 32; off > 0; off >>= 1) sm += __shfl_xor(sm, off);
    if (lane == 0) red[wv] = sm;
    __syncthreads();
    const float gs = red[0] + red[1] + red[2] + red[3];
    if (t < 128) {
        const float w = ex / gs;
        w_s[t] = w;
        if (s == 0) attnw[(size_t)b * L_ + t] = w;
    }
    __syncthreads();

    const int h = s * 256 + t;
    const float* encb = enc + (size_t)b * H_ + h;
    float c = 0.f;
#pragma unroll 4
    for (int l = 0; l < 128; l++)
        c += w_s[l] * encb[(size_t)l * (B_ * H_)];
    cat_hi[(size_t)b * 2048 + 1024 + h] = f2bf(c);
}

// co = tanh(sum of 4 partials + b_cat) -> bf16
__global__ __launch_bounds__(256) void co_reduce_kernel(
    const float* __restrict__ co_part, const float* __restrict__ b_cat,
    unsigned short* __restrict__ co_hi)
{
    const int id = blockIdx.x * 256 + threadIdx.x;
    const int j = id & 1023;
    float s = b_cat[j];
#pragma unroll
    for (int p = 0; p < 4; p++) s += co_part[(size_t)p * 131072 + id];
    co_hi[id] = f2bf(tanhf(s));
}

// ---------------------------------------------------------------------------
extern "C" void kernel_launch(void* const* d_in, const int* in_sizes, int n_in,
                              void* d_out, int out_size, void* d_ws, size_t ws_size,
                              hipStream_t stream)
{
    const int*   seq    = (const int*)  d_in[0];
    const float* lh     = (const float*)d_in[1];
    const float* enc    = (const float*)d_in[2];
    const int*   c2n    = (const int*)  d_in[3];
    const int*   c2f    = (const int*)  d_in[4];
    const float* emb    = (const float*)d_in[5];
    const float* semb   = (const float*)d_in[6];
    const float* nemb   = (const float*)d_in[7];
    const float* W_ih   = (const float*)d_in[8];
    const float* W_hh   = (const float*)d_in[9];
    const float* b_ih   = (const float*)d_in[10];
    const float* b_hh   = (const float*)d_in[11];
    const float* W_attn = (const float*)d_in[12];
    // d_in[13] = b_attn: dropped (softmax shift-invariant, exact)
    const float* W_cat  = (const float*)d_in[14];
    const float* b_cat  = (const float*)d_in[15];
    const float* W_out  = (const float*)d_in[16];
    const float* b_out  = (const float*)d_in[17];

    float* out    = (float*)d_out;
    float* hidden = out + (size_t)B_ * V_;
    float* attnw  = hidden + (size_t)B_ * H_;

    // ---- workspace layout ----
    unsigned short* x_hi   = (unsigned short*)d_ws;            // 128*1088
    unsigned short* x_lo   = x_hi   + (size_t)128 * INDIM;
    unsigned short* h_hi   = x_lo   + (size_t)128 * INDIM;     // 128*1024
    unsigned short* h_lo   = h_hi   + (size_t)128 * 1024;
    unsigned short* cat_hi = h_lo   + (size_t)128 * 1024;      // 128*2048
    unsigned short* cat_lo = cat_hi + (size_t)128 * 2048;
    unsigned short* co_hi  = cat_lo + (size_t)128 * 2048;      // 128*1024
    float* fbase   = (float*)(co_hi + (size_t)128 * 1024);
    float* gi_part = fbase;                                    // 4*128*3072
    float* gh_part = gi_part + (size_t)4 * 128 * 3072;         // 4*128*3072
    // aliases (gi/gh dead after gates):
    float* q_part  = fbase;                                    // 4*128*1024
    float* co_part = q_part + (size_t)4 * 128 * 1024;          // 4*128*1024
    float* epart   = co_part + (size_t)4 * 128 * 1024;         // 128*128*4

    const int SMEM_SPLIT = 55296;
    const int SMEM_PLAIN = 27648;

    // 1. prep: x, h bf16 hi/lo planes
    hipLaunchKernelGGL(prep_kernel, dim3(B_), dim3(256), 0, stream,
                       seq, c2n, c2f, emb, semb, nemb, lh, x_hi, x_lo, h_hi, h_lo);
    // 2+3. gi & gh partials in one dispatch (z selects), PLAIN bf16
    hipLaunchKernelGGL(gru_gemm, dim3(48, 4, 2), dim3(256), SMEM_PLAIN, stream,
                       x_hi, W_ih, h_hi, W_hh, gi_part, gh_part);
    // 4. gates -> hidden + cat planes
    hipLaunchKernelGGL(gru_gates_kernel, dim3(512), dim3(256), 0, stream,
                       gi_part, gh_part, b_ih, b_hh, lh, hidden, cat_hi, cat_lo);
    // 5. q partials (split) + W_cat h-half (plain, co_part slices 0/1)
    hipLaunchKernelGGL(q_cat_kernel, dim3(16, 4, 2), dim3(256), SMEM_SPLIT, stream,
                       cat_hi, cat_lo, W_attn, W_cat, q_part, co_part);
    // 6. energies
    hipLaunchKernelGGL(energy_partial_kernel, dim3(4, 128), dim3(512), 0, stream,
                       q_part, enc, epart);
    // 7. softmax + context fused
    hipLaunchKernelGGL(context_softmax_kernel, dim3(4, 128), dim3(256), 0, stream,
                       epart, enc, cat_hi, attnw);
    // 8. W_cat ctx-half: A = ctx columns, W = W_cat[:,1024:], co_part slices 2/3
    hipLaunchKernelGGL((sgemm<true, false, false>), dim3(16, 2), dim3(256), SMEM_PLAIN, stream,
                       cat_hi + 1024, cat_hi + 1024, 2048, W_cat + 1024, 2048,
                       (const float*)nullptr,
                       co_part + (size_t)2 * 128 * 1024, H_, (size_t)128 * 1024,
                       H_, 512, 512);
    // 9. co = tanh(sum + b_cat) -> bf16
    hipLaunchKernelGGL(co_reduce_kernel, dim3(512), dim3(256), 0, stream,
                       co_part, b_cat, co_hi);
    // 10. out = co @ W_out.T + b_out (depth-2 W prefetch)
    hipLaunchKernelGGL((sgemm<true, false, false>), dim3((V_ + 63) / 64, 1), dim3(256), SMEM_PLAIN, stream,
                       co_hi, co_hi, H_, W_out, H_, b_out,
                       out, V_, (size_t)0, V_, H_, H_);
}